// Round 2
// baseline (326.979 us; speedup 1.0000x reference)
//
#include <hip/hip_runtime.h>

typedef float f32x4 __attribute__((ext_vector_type(4)));

// Tiny pre-kernel: filter sums -> ws[0..3] = {sum(gl), sum(gh), sum(fl), sum(fh)}
__global__ void qwt_sums_kernel(const float* __restrict__ gl, const float* __restrict__ gh,
                                const float* __restrict__ fl, const float* __restrict__ fh,
                                float* __restrict__ ws) {
    int t = threadIdx.x;
    if (t < 4) {
        const float* p = (t == 0) ? gl : (t == 1) ? gh : (t == 2) ? fl : fh;
        float s = 0.f;
        #pragma unroll
        for (int i = 0; i < 16; i++) s += p[i];
        ws[t] = s;
    }
}

// One wave (64 lanes) == FOUR consecutive output rows (4 px/lane/row).
// grid: 1024 blocks x 256 threads = 4096 waves = (4*16*256)/4 row-groups.
// Stores are plane-major: per plane a wave writes a 4 KB contiguous burst
// (4 rows x 1 KB), vs the previous 1 KB scatter across 16 planes.
__global__ __launch_bounds__(256) void qwt_main_kernel(const float* __restrict__ img,
                                                       const float* __restrict__ ws,
                                                       float* __restrict__ out) {
    const float w0 = -0.09375f, w1 = 0.59375f;  // CUBIC_W = {w0, w1, w1, w0}

    int t    = blockIdx.x * 256 + threadIdx.x;
    int lane = t & 63;
    int wid  = t >> 6;         // 0..4095
    int ygrp = wid & 63;       // 64 groups of 4 output rows
    int bc   = wid >> 6;       // 0..63 = b*16 + c
    int y0   = ygrp << 2;      // first output row of this wave
    int x0   = lane << 2;      // 4 output px per lane per row

    // load scales early (uniform, L1-broadcast)
    float sg = ws[0], sh = ws[1], sfl = ws[2], sfh = ws[3];

    const float* src = img + (size_t)bc * (512 * 512);

    // Horizontal pass over the 10 unique source rows: 2*y0-1 .. 2*y0+8 (clamped).
    // h[k][i] = horizontal bicubic at output col x0+i for source row k.
    float h[10][4];
    #pragma unroll
    for (int k = 0; k < 10; k++) {
        int sr = 2 * y0 - 1 + k;                     // wave-uniform
        sr = sr < 0 ? 0 : (sr > 511 ? 511 : sr);
        const f32x4* rp4 = (const f32x4*)(src + (size_t)sr * 512);
        f32x4 v0 = rp4[2 * lane];
        f32x4 v1 = rp4[2 * lane + 1];
        float left  = __shfl_up(v1.w, 1);            // col 8*lane - 1
        float right = __shfl_down(v0.x, 1);          // col 8*lane + 8
        if (lane == 0)  left  = v0.x;                // clamp col -1 -> 0
        if (lane == 63) right = v1.w;                // clamp col 512 -> 511

        h[k][0] = w0 * left + w1 * v0.x + w1 * v0.y + w0 * v0.z;
        h[k][1] = w0 * v0.y + w1 * v0.z + w1 * v0.w + w0 * v1.x;
        h[k][2] = w0 * v0.w + w1 * v1.x + w1 * v1.y + w0 * v1.z;
        h[k][3] = w0 * v1.y + w1 * v1.z + w1 * v1.w + w0 * right;
    }

    // Vertical pass: acc[r][i] = downsampled value at (y0+r, x0+i).
    f32x4 acc[4];
    #pragma unroll
    for (int r = 0; r < 4; r++) {
        #pragma unroll
        for (int i = 0; i < 4; i++) {
            float a = w0 * h[2 * r][i] + w1 * h[2 * r + 1][i]
                    + w1 * h[2 * r + 2][i] + w0 * h[2 * r + 3][i];
            acc[r][i] = a;
        }
    }

    int b   = bc >> 4;          // batch 0..3
    int cc_ = bc & 15;          // channel 0..15
    size_t rowoff = ((size_t)y0 << 8) + (size_t)x0;  // y0*256 + x0
    const size_t P  = 65536;                         // 256*256
    const size_t HB = 16777216;                      // LL element count

    float* llp = out + ((size_t)(b * 64 + cc_)) * P + rowoff;
    float* hp  = out + HB + ((size_t)(b * 64 + cc_)) * 3 * P + rowoff;

    #pragma unroll
    for (int q = 0; q < 4; q++) {
        float f1g = (q & 1) ? sfl : sg;
        float f1h = (q & 1) ? sfh : sh;
        float f2g = (q & 2) ? sfl : sg;
        float f2h = (q & 2) ? sfh : sh;

        float sLL = f1g * f2g;
        float s0  = f1g * f2h;
        float s1  = f1h * f2g;
        float s2  = f1h * f2h;

        // 4-row contiguous bursts per plane; row steps fold into 13-bit store imms.
        #pragma unroll
        for (int r = 0; r < 4; r++) {
            f32x4 v = {acc[r][0] * sLL, acc[r][1] * sLL, acc[r][2] * sLL, acc[r][3] * sLL};
            *(f32x4*)(llp + r * 256) = v;
        }
        #pragma unroll
        for (int r = 0; r < 4; r++) {
            f32x4 v = {acc[r][0] * s0, acc[r][1] * s0, acc[r][2] * s0, acc[r][3] * s0};
            *(f32x4*)(hp + r * 256) = v;
        }
        #pragma unroll
        for (int r = 0; r < 4; r++) {
            f32x4 v = {acc[r][0] * s1, acc[r][1] * s1, acc[r][2] * s1, acc[r][3] * s1};
            *(f32x4*)(hp + P + r * 256) = v;
        }
        #pragma unroll
        for (int r = 0; r < 4; r++) {
            f32x4 v = {acc[r][0] * s2, acc[r][1] * s2, acc[r][2] * s2, acc[r][3] * s2};
            *(f32x4*)(hp + 2 * P + r * 256) = v;
        }

        llp += 16 * P;
        hp  += 48 * P;
    }
}

extern "C" void kernel_launch(void* const* d_in, const int* in_sizes, int n_in,
                              void* d_out, int out_size, void* d_ws, size_t ws_size,
                              hipStream_t stream) {
    const float* img = (const float*)d_in[0];
    const float* gl  = (const float*)d_in[1];
    const float* gh  = (const float*)d_in[2];
    const float* fl  = (const float*)d_in[3];
    const float* fh  = (const float*)d_in[4];
    float* out = (float*)d_out;
    float* ws  = (float*)d_ws;

    qwt_sums_kernel<<<1, 64, 0, stream>>>(gl, gh, fl, fh, ws);
    // 4096 waves, 4 output rows each
    qwt_main_kernel<<<1024, 256, 0, stream>>>(img, ws, out);
}